// Round 5
// baseline (121.333 us; speedup 1.0000x reference)
//
#include <hip/hip_runtime.h>

typedef unsigned char u8;
typedef unsigned short u16;
typedef float f32x4 __attribute__((ext_vector_type(4)));
typedef int i32x4 __attribute__((ext_vector_type(4)));
typedef int i32x8 __attribute__((ext_vector_type(8)));

#define NROWS 16384
#define DIM 128

// exp(-2*sim) = exp2(sim * -2*log2(e)); scale folded into normalized B rows.
#define NEG2LOG2E -2.8853900817779268f
#define SCALE ((float)(1.0 / (16384.0 * 16383.0)))

// E8M0 scale byte 127 = 2^0 = 1.0, replicated.
#define SCALE1 0x7F7F7F7F

#define KMAX 320
#define NCORR 100
#define NGEMM 4096

// Two rows per wave (half-wave per row): float4 loads, half-wave shuffle
// reduction, paired cvt_pk_fp8 -> one dword store per lane (fully coalesced).
// B rows pre-scaled by -2*log2(e) so GEMM output feeds exp2 directly.
__global__ __launch_bounds__(256) void norm_kernel(
    const float* __restrict__ a, const float* __restrict__ b,
    u8* __restrict__ aO, u8* __restrict__ bO)
{
    int tid  = threadIdx.x;
    int lane = tid & 63;
    int w    = tid >> 6;
    int half = lane >> 5;
    int l32  = lane & 31;
    long row = (long)blockIdx.x * 8 + w * 2 + half;

    const float4 va = ((const float4*)(a + row * DIM))[l32];
    float sa = va.x * va.x + va.y * va.y + va.z * va.z + va.w * va.w;
    #pragma unroll
    for (int off = 16; off; off >>= 1) sa += __shfl_xor(sa, off, 64);
    float inva = 1.0f / fmaxf(sqrtf(sa), 1e-12f);
    int pa = __builtin_amdgcn_cvt_pk_fp8_f32(va.x * inva, va.y * inva, 0, false);
    pa = __builtin_amdgcn_cvt_pk_fp8_f32(va.z * inva, va.w * inva, pa, true);
    ((int*)(aO + row * DIM))[l32] = pa;

    const float4 vb = ((const float4*)(b + row * DIM))[l32];
    float sb = vb.x * vb.x + vb.y * vb.y + vb.z * vb.z + vb.w * vb.w;
    #pragma unroll
    for (int off = 16; off; off >>= 1) sb += __shfl_xor(sb, off, 64);
    float invb = NEG2LOG2E / fmaxf(sqrtf(sb), 1e-12f);
    int pb = __builtin_amdgcn_cvt_pk_fp8_f32(vb.x * invb, vb.y * invb, 0, false);
    pb = __builtin_amdgcn_cvt_pk_fp8_f32(vb.z * invb, vb.w * invb, pb, true);
    ((int*)(bO + row * DIM))[l32] = pb;
}

// 1D grid of 100 + 4096 blocks. IDs 0..99: correction blocks (early, so
// their latency chains hide under gemm warm-up). IDs 100+: maskless GEMM.
//
// R15: in-wave software pipeline. R10 (barriered) and R14 (barrier-free)
// both landed ~52-60us with identical profiles -> the bottleneck is the
// per-chunk serial chain ds_read -> 8 MFMA -> 32 exp2 (exp2 depends on
// acc), which alternates matrix/VALU phases within each wave; 3 waves/SIMD
// can't cover it. Fix: two acc sets (A/B parity). Iteration i issues the
// 8 MFMAs of chunk i+1 INTERLEAVED 1:8 with the 64 exp2/add ops of chunk i
// (sched_group_barrier; one MFMA ~34cy ~= one 4exp2+4add group ~40cy, so
// a single wave feeds both pipes). Barrier-free per-wave-private staging
// kept from R14 (counted vmcnt(4), zero __syncthreads in the main loop).
// XOR-swizzle kept: inverse-swizzled global source + swizzled ds_read.
__global__ __launch_bounds__(256, 3) void gemm_kernel(
    const u8* __restrict__ A, const u8* __restrict__ B,
    const int* __restrict__ labels,
    float* __restrict__ partials, float* __restrict__ corrP)
{
    __shared__ u8 sStage[4][2][4096];     // [wave][buf][32 rows x 128B]
    __shared__ int sIdx[KMAX];
    __shared__ float redS[4];
    __shared__ int sCnt;

    int tid  = threadIdx.x;
    int lane = tid & 63;
    int w    = tid >> 6;
    int mrow = lane & 15;
    int q    = lane >> 4;

    if (blockIdx.x < NCORR) {
        // ---------------- correction path (early blocks) ----------------
        int l = blockIdx.x;
        if (tid == 0) sCnt = 0;
        __syncthreads();

        for (int i = tid; i < NROWS; i += 256)
            if (labels[i] == l) {
                int p = atomicAdd(&sCnt, 1);
                if (p < KMAX) sIdx[p] = i;
            }
        __syncthreads();

        int k = sCnt < KMAX ? sCnt : KMAX;
        int nt = (k + 15) >> 4;
        int ntk = nt << 4;
        for (int r = k + tid; r < ntk; r += 256) sIdx[r] = sIdx[0];  // pad
        __syncthreads();

        int npairs = nt * nt;
        float s = 0.0f;
        // 2-deep software pipeline: two tile-pairs per iteration, gathers
        // issued together so their L2 latency overlaps.
        for (int tp = w; tp < npairs; tp += 8) {
            int tpB = tp + 4;
            bool has2 = tpB < npairs;
            int tp2 = has2 ? tpB : tp;

            int ti1 = tp / nt,  tj1 = tp  - ti1 * nt;
            int ti2 = tp2 / nt, tj2 = tp2 - ti2 * nt;
            int ri1 = sIdx[ti1 * 16 + mrow], rj1 = sIdx[tj1 * 16 + mrow];
            int ri2 = sIdx[ti2 * 16 + mrow], rj2 = sIdx[tj2 * 16 + mrow];

            const u8* pa1 = A + (size_t)ri1 * DIM + q * 32;
            const u8* pb1 = B + (size_t)rj1 * DIM + q * 32;
            const u8* pa2 = A + (size_t)ri2 * DIM + q * 32;
            const u8* pb2 = B + (size_t)rj2 * DIM + q * 32;

            i32x8 aF1, bF1, aF2, bF2;
            *((i32x4*)&aF1)     = *(const i32x4*)pa1;
            *((i32x4*)&aF1 + 1) = *(const i32x4*)(pa1 + 16);
            *((i32x4*)&bF1)     = *(const i32x4*)pb1;
            *((i32x4*)&bF1 + 1) = *(const i32x4*)(pb1 + 16);
            *((i32x4*)&aF2)     = *(const i32x4*)pa2;
            *((i32x4*)&aF2 + 1) = *(const i32x4*)(pa2 + 16);
            *((i32x4*)&bF2)     = *(const i32x4*)pb2;
            *((i32x4*)&bF2 + 1) = *(const i32x4*)(pb2 + 16);

            f32x4 acc1 = (f32x4){0.f, 0.f, 0.f, 0.f};
            f32x4 acc2 = (f32x4){0.f, 0.f, 0.f, 0.f};
            acc1 = __builtin_amdgcn_mfma_scale_f32_16x16x128_f8f6f4(
                aF1, bF1, acc1, 0, 0, 0, SCALE1, 0, SCALE1);
            acc2 = __builtin_amdgcn_mfma_scale_f32_16x16x128_f8f6f4(
                aF2, bF2, acc2, 0, 0, 0, SCALE1, 0, SCALE1);

            int i1 = ti1 * 16 + q * 4, j1 = tj1 * 16 + mrow;
            int i2 = ti2 * 16 + q * 4, j2 = tj2 * 16 + mrow;
            #pragma unroll
            for (int r = 0; r < 4; r++) {
                float e1 = __builtin_amdgcn_exp2f(acc1[r]);
                s += ((i1 + r) < k && j1 < k) ? e1 : 0.0f;
                float e2 = __builtin_amdgcn_exp2f(acc2[r]);
                s += (has2 && (i2 + r) < k && j2 < k) ? e2 : 0.0f;
            }
        }

        #pragma unroll
        for (int off = 32; off; off >>= 1) s += __shfl_xor(s, off, 64);
        if (lane == 0) redS[w] = s;
        __syncthreads();
        if (tid == 0)
            corrP[l] = (redS[0] + redS[1] + redS[2] + redS[3]) * SCALE;
        return;
    }

    // ---------------- maskless GEMM path (in-wave pipelined) ----------------
    int g  = blockIdx.x - NCORR;
    int r0 = (g & 255) * 64;                 // A row panel (64 rows)
    int c0 = (g >> 8) * 1024 + w * 256;      // this wave's B col panel

    // A fragments direct global->VGPR (L2-resident; proven addressing).
    i32x8 a8[4];
    #pragma unroll
    for (int mi = 0; mi < 4; mi++) {
        const u8* pa = A + (size_t)(r0 + mi * 16 + mrow) * DIM + q * 32;
        *((i32x4*)&a8[mi])     = *(const i32x4*)pa;
        *((i32x4*)&a8[mi] + 1) = *(const i32x4*)(pa + 16);
    }

    // Per-lane inverse-swizzled global source offset for staging:
    // lane covers row m = i*8 + (lane>>3), granule p = lane&7 of the chunk;
    // source granule = p ^ (m&7); m&7 == (lane>>3)&7 regardless of i.
    int laneSrc = (lane >> 3) * DIM + (((lane & 7) ^ ((lane >> 3) & 7)) << 4);
    const u8* gBw = B + (size_t)c0 * DIM + laneSrc;
    u8* myStage = &sStage[w][0][0];

#define STAGE(ct, buf) do {                                                   \
        const u8* gp_ = gBw + (size_t)(ct) * (32 * DIM);                      \
        u8* lp_ = myStage + (buf) * 4096;                                     \
        _Pragma("unroll")                                                     \
        for (int i_ = 0; i_ < 4; i_++) {                                      \
            __builtin_amdgcn_global_load_lds(                                 \
                (const __attribute__((address_space(1))) void*)(gp_ + i_ * 1024), \
                (__attribute__((address_space(3))) void*)(lp_ + i_ * 1024),   \
                16, 0, 0);                                                    \
        } } while (0)

    // Swizzled read offsets within a 4KB chunk: row n (0..31), granules
    // 2q / 2q+1 live at byte n*128 + (((2q)^(n&7))<<4) and that ^16.
    int bOff[2];
    #pragma unroll
    for (int ni = 0; ni < 2; ni++) {
        int n = ni * 16 + mrow;
        bOff[ni] = n * DIM + (((q << 1) ^ (n & 7)) << 4);
    }

#define READB8(B8, BUF) do {                                                  \
        const u8* sb_ = myStage + (BUF) * 4096;                               \
        _Pragma("unroll")                                                     \
        for (int ni_ = 0; ni_ < 2; ni_++) {                                   \
            *((i32x4*)&(B8)[ni_])     = *(const i32x4*)(sb_ + bOff[ni_]);     \
            *((i32x4*)&(B8)[ni_] + 1) = *(const i32x4*)(sb_ + (bOff[ni_] ^ 16)); \
        } } while (0)

#define MFMA8(ACC, B8) do {                                                   \
        _Pragma("unroll")                                                     \
        for (int mi_ = 0; mi_ < 4; mi_++)                                     \
            _Pragma("unroll")                                                 \
            for (int ni_ = 0; ni_ < 2; ni_++)                                 \
                (ACC)[mi_][ni_] = __builtin_amdgcn_mfma_scale_f32_16x16x128_f8f6f4( \
                    a8[mi_], (B8)[ni_], z4, 0, 0, 0, SCALE1, 0, SCALE1);      \
        } while (0)

#define EXP32(ACC) do {                                                       \
        _Pragma("unroll")                                                     \
        for (int mi_ = 0; mi_ < 4; mi_++)                                     \
            _Pragma("unroll")                                                 \
            for (int ni_ = 0; ni_ < 2; ni_++) {                               \
                s0 += __builtin_amdgcn_exp2f((ACC)[mi_][ni_][0]);             \
                s1 += __builtin_amdgcn_exp2f((ACC)[mi_][ni_][1]);             \
                s2 += __builtin_amdgcn_exp2f((ACC)[mi_][ni_][2]);             \
                s3 += __builtin_amdgcn_exp2f((ACC)[mi_][ni_][3]);             \
            } } while (0)

    // 1 MFMA (~34cy) per 8 VALU (4 exp2 + 4 add, ~40cy): both pipes fed
    // from one wave. Masks: MFMA=0x8, VALU=0x2.
#define SGB_INTERLEAVE() do {                                                 \
        _Pragma("unroll")                                                     \
        for (int k_ = 0; k_ < 8; k_++) {                                      \
            __builtin_amdgcn_sched_group_barrier(0x8, 1, 0);                  \
            __builtin_amdgcn_sched_group_barrier(0x2, 8, 0);                  \
        } } while (0)

    STAGE(0, 0);
    STAGE(1, 1);

    const f32x4 z4 = (f32x4){0.f, 0.f, 0.f, 0.f};
    float s0 = 0.0f, s1 = 0.0f, s2 = 0.0f, s3 = 0.0f;

    f32x4 accA[4][2], accB[4][2];
    i32x8 b8[2];

    // Prologue: a8 + chunk0 resident (8 a8-loads + 4 stage0 are the oldest
    // 12 of 16 outstanding; vmcnt(4) leaves stage1 in flight).
    asm volatile("s_waitcnt vmcnt(4)" ::: "memory");
    __builtin_amdgcn_sched_barrier(0);
    READB8(b8, 0);
    asm volatile("s_waitcnt lgkmcnt(0)" ::: "memory");
    __builtin_amdgcn_sched_barrier(0);
    MFMA8(accA, b8);     // chunk 0 -> set A

    // Steady state: iteration i computes MFMA(chunk i+1) into set (i+1)&1
    // while running exp2 on set i&1 (chunk i), interleaved 1:8.
    #pragma unroll
    for (int i = 0; i < 7; ++i) {
        if (i < 6) {
            STAGE(i + 2, i & 1);   // buf (i+2)&1 == i&1; chunk i read last iter
            // stage(i+1) (issued one full compute phase ago) must land;
            // the 4 just-issued stay in flight.
            asm volatile("s_waitcnt vmcnt(4)" ::: "memory");
        } else {
            asm volatile("s_waitcnt vmcnt(0)" ::: "memory");
        }
        __builtin_amdgcn_sched_barrier(0);

        READB8(b8, (i + 1) & 1);
        asm volatile("s_waitcnt lgkmcnt(0)" ::: "memory");
        __builtin_amdgcn_sched_barrier(0);

        if ((i & 1) == 0) { MFMA8(accB, b8); EXP32(accA); }
        else              { MFMA8(accA, b8); EXP32(accB); }
        SGB_INTERLEAVE();
    }
    EXP32(accB);   // chunk 7 (set 7&1 = B)

#undef STAGE
#undef READB8
#undef MFMA8
#undef EXP32
#undef SGB_INTERLEAVE

    float s = (s0 + s1) + (s2 + s3);
    #pragma unroll
    for (int off = 32; off; off >>= 1) s += __shfl_xor(s, off, 64);

    if (lane == 0) redS[w] = s;
    __syncthreads();
    if (tid == 0) {
        float t = (redS[0] + redS[1]) + (redS[2] + redS[3]);
        partials[g] = t * SCALE;
    }
}

__global__ __launch_bounds__(256) void reduce_kernel(
    const float* __restrict__ gP, const float* __restrict__ cP,
    float* __restrict__ out)
{
    int tid = threadIdx.x;
    const float4* p4 = (const float4*)gP;
    float s = 0.0f;
    #pragma unroll 4
    for (int i = tid; i < 1024; i += 256) {
        float4 v = p4[i];
        s += (v.x + v.y) + (v.z + v.w);
    }
    if (tid < NCORR) s -= cP[tid];
    #pragma unroll
    for (int off = 32; off; off >>= 1) s += __shfl_xor(s, off, 64);
    __shared__ float red[4];
    if ((tid & 63) == 0) red[tid >> 6] = s;
    __syncthreads();
    if (tid == 0) out[0] = (red[0] + red[1]) + (red[2] + red[3]);
}

extern "C" void kernel_launch(void* const* d_in, const int* in_sizes, int n_in,
                              void* d_out, int out_size, void* d_ws, size_t ws_size,
                              hipStream_t stream) {
    const float* self_p = (const float*)d_in[0];
    const float* pos_p  = (const float*)d_in[1];
    const int*   labels = (const int*)d_in[2];
    float* out = (float*)d_out;

    u8* aB = (u8*)d_ws;                         // 2 MB fp8 normalized self
    u8* bB = aB + (size_t)NROWS * DIM;          // 2 MB fp8 normalized pos (pre-scaled)
    float* gemmP = (float*)(bB + (size_t)NROWS * DIM);     // 16 KB
    float* corrP = gemmP + NGEMM;                           // 400 B (100 used)

    norm_kernel<<<NROWS / 8, 256, 0, stream>>>(self_p, pos_p, aB, bB);
    gemm_kernel<<<NCORR + NGEMM, 256, 0, stream>>>(aB, bB, labels, gemmP, corrP);
    reduce_kernel<<<1, 256, 0, stream>>>(gemmP, corrP, out);
}